// Round 2
// baseline (7112.341 us; speedup 1.0000x reference)
//
#include <hip/hip_runtime.h>
#include <hip/hip_bf16.h>

typedef __hip_bfloat16 bf16;

static constexpr int BATCH = 4;
static constexpr int TPTS  = 65536;
static constexpr int NPTS  = BATCH * TPTS;    // 262144
static constexpr int R3    = 32768;
static constexpr int PPB   = 16;              // points per block (4 waves x 4)

__device__ inline float us2f(unsigned short u) {
  return __uint_as_float(((unsigned)u) << 16);
}
__device__ inline unsigned enc_max(float f) {
  unsigned u = __float_as_uint(f);
  return (u & 0x80000000u) ? ~u : (u | 0x80000000u);
}
__device__ inline float dec_max(unsigned u) {
  return __uint_as_float((u & 0x80000000u) ? (u & 0x7fffffffu) : ~u);
}

// Staged GEMV piece: all 256 threads stage `rows`x128 f32 weights into swb,
// then each wave accumulates its 4 points. Lane owns channels {2l, 2l+1}.
// relu_x: apply relu to x before multiply.
template <bool RELU>
__device__ inline void staged_fc128(const float* __restrict__ w, int K,
                                    float* __restrict__ swb,
                                    const float (*sx)[256], int pt0, int xoff,
                                    int lane, float2 a[4])
{
  const int n = 2 * lane;
  for (int k0 = 0; k0 < K; k0 += 64) {
    __syncthreads();
    const float4* src = (const float4*)(w + (size_t)k0 * 128);
    float4* dst = (float4*)swb;
    for (int i = threadIdx.x; i < 2048; i += 256) dst[i] = src[i];
    __syncthreads();
#pragma unroll 4
    for (int kk = 0; kk < 64; ++kk) {
      float2 wv2 = *(const float2*)(swb + kk * 128 + n);
#pragma unroll
      for (int j = 0; j < 4; ++j) {
        float xv = sx[pt0 + j][xoff + k0 + kk];
        if (RELU) xv = fmaxf(xv, 0.0f);
        a[j].x += xv * wv2.x;
        a[j].y += xv * wv2.y;
      }
    }
  }
}

// Full ResnetBlockFC for 16 points (4 per wave). sx[pt][0..255] staged input.
__device__ inline void resblock16(float* __restrict__ swb,
                                  float (*sx)[256], float (*sh)[128],
                                  const float* __restrict__ w0, const float* __restrict__ b0,
                                  const float* __restrict__ w1, const float* __restrict__ b1,
                                  const float* __restrict__ wsc,
                                  int wv, int lane, int tbase, bf16* __restrict__ net)
{
  const int n = 2 * lane;
  const int pt0 = wv * 4;

  // fc0: relu(x) @ w0 + b0  -> relu -> sh
  float2 a[4];
  {
    float2 bb = *(const float2*)(b0 + n);
#pragma unroll
    for (int j = 0; j < 4; ++j) a[j] = bb;
  }
  staged_fc128<true>(w0, 256, swb, (const float(*)[256])sx, pt0, 0, lane, a);
#pragma unroll
  for (int j = 0; j < 4; ++j) {
    sh[pt0 + j][n]     = fmaxf(a[j].x, 0.0f);
    sh[pt0 + j][n + 1] = fmaxf(a[j].y, 0.0f);
  }

  // fc1: sh @ w1 + b1  (sh already relu'd)
  float2 d[4];
  {
    float2 bb = *(const float2*)(b1 + n);
#pragma unroll
    for (int j = 0; j < 4; ++j) d[j] = bb;
  }
  {
    const int K = 128;
    for (int k0 = 0; k0 < K; k0 += 64) {
      __syncthreads();
      const float4* src = (const float4*)(w1 + (size_t)k0 * 128);
      float4* dst = (float4*)swb;
      for (int i = threadIdx.x; i < 2048; i += 256) dst[i] = src[i];
      __syncthreads();
#pragma unroll 4
      for (int kk = 0; kk < 64; ++kk) {
        float2 wv2 = *(const float2*)(swb + kk * 128 + n);
#pragma unroll
        for (int j = 0; j < 4; ++j) {
          float hv = sh[pt0 + j][k0 + kk];
          d[j].x += hv * wv2.x;
          d[j].y += hv * wv2.y;
        }
      }
    }
  }

  // shortcut: x @ wsc (no bias, no relu), add into d
  staged_fc128<false>(wsc, 256, swb, (const float(*)[256])sx, pt0, 0, lane, d);

  // write net rows (bf16)
#pragma unroll
  for (int j = 0; j < 4; ++j) {
    int t = tbase + pt0 + j;
    __hip_bfloat162 o;
    o.x = __float2bfloat16(d[j].x);
    o.y = __float2bfloat16(d[j].y);
    *(__hip_bfloat162*)(net + (size_t)t * 128 + n) = o;
  }
}

// grid index + pos_enc + fc_pos + resblock 0
__global__ __launch_bounds__(256) void k_first(
    const float* __restrict__ p,
    const float* __restrict__ wpos, const float* __restrict__ bpos,
    const float* __restrict__ w0,  const float* __restrict__ b0,
    const float* __restrict__ w1,  const float* __restrict__ b1,
    const float* __restrict__ wsc,
    bf16* __restrict__ net, int* __restrict__ idxbuf)
{
  __shared__ float swb[8192];        // 32 KB weight chunk
  __shared__ float sx[PPB][256];
  __shared__ float sh[PPB][128];
  __shared__ float se[PPB][64];
  const int wv = threadIdx.x >> 6, lane = threadIdx.x & 63;
  const int tbase = blockIdx.x * PPB;
  const int pt0 = wv * 4;

#pragma unroll
  for (int j = 0; j < 4; ++j) {
    const int t = tbase + pt0 + j;
    const float px = p[t * 3 + 0];
    const float py = p[t * 3 + 1];
    const float pz = p[t * 3 + 2];
    if (lane == 0) {
      float nx = fminf(fmaxf(px / 1.101f + 0.5f, 0.0f), 0.999f);
      float ny = fminf(fmaxf(py / 1.101f + 0.5f, 0.0f), 0.999f);
      float nz = fminf(fmaxf(pz / 1.101f + 0.5f, 0.0f), 0.999f);
      int xi = (int)(nx * 32.0f);
      int yi = (int)(ny * 32.0f);
      int zi = (int)(nz * 32.0f);
      idxbuf[t] = xi + 32 * yi + 1024 * zi;
    }
    if (lane < 60) {
      int i = lane / 6, r = lane % 6, comp = r % 3;
      float pc = (comp == 0) ? px : ((comp == 1) ? py : pz);
      float f = exp2f((float)i) * 3.14159274101257324f;
      float ang = f * pc;
      se[pt0 + j][lane] = (r < 3) ? sinf(ang) : cosf(ang);
    }
  }

  // fc_pos: 60 -> 256. lane owns out channels 4l..4l+3, per point.
  const int n4 = 4 * lane;
  float acc[4][4];
  {
    float4 bb = *(const float4*)(bpos + n4);
#pragma unroll
    for (int j = 0; j < 4; ++j) {
      acc[j][0] = bb.x; acc[j][1] = bb.y; acc[j][2] = bb.z; acc[j][3] = bb.w;
    }
  }
  int k0 = 0;
  for (int c = 0; c < 2; ++c) {
    const int rows = c ? 28 : 32;
    __syncthreads();
    const float4* src = (const float4*)(wpos + (size_t)k0 * 256);
    float4* dst = (float4*)swb;
    const int cnt4 = rows * 64;
    for (int i = threadIdx.x; i < cnt4; i += 256) dst[i] = src[i];
    __syncthreads();
    for (int kk = 0; kk < rows; ++kk) {
      float4 w4 = *(const float4*)(swb + kk * 256 + n4);
#pragma unroll
      for (int j = 0; j < 4; ++j) {
        float e = se[pt0 + j][k0 + kk];
        acc[j][0] += e * w4.x;
        acc[j][1] += e * w4.y;
        acc[j][2] += e * w4.z;
        acc[j][3] += e * w4.w;
      }
    }
    k0 += rows;
  }
#pragma unroll
  for (int j = 0; j < 4; ++j) {
    float4* dstx = (float4*)(&sx[pt0 + j][n4]);
    *dstx = make_float4(acc[j][0], acc[j][1], acc[j][2], acc[j][3]);
  }

  resblock16(swb, sx, sh, w0, b0, w1, b1, wsc, wv, lane, tbase, net);
}

// scatter-max of net into fea (encoded uint)
__global__ __launch_bounds__(256) void k_pool(
    const unsigned short* __restrict__ net, const int* __restrict__ idxbuf,
    unsigned* __restrict__ fea)
{
  const int gid = blockIdx.x * 256 + threadIdx.x;
  const int t = gid >> 7, c = gid & 127;
  const int b = t >> 16;
  const int v = idxbuf[t];
  float val = us2f(net[gid]);
  atomicMax(&fea[(((size_t)((b << 15) | v)) << 7) + c], enc_max(val));
}

// gather pooled + concat + resblock i (net updated in place)
__global__ __launch_bounds__(256) void k_res(
    bf16* __restrict__ net, const unsigned* __restrict__ fea, const int* __restrict__ idxbuf,
    const float* __restrict__ w0, const float* __restrict__ b0,
    const float* __restrict__ w1, const float* __restrict__ b1,
    const float* __restrict__ wsc)
{
  __shared__ float swb[8192];
  __shared__ float sx[PPB][256];
  __shared__ float sh[PPB][128];
  const int wv = threadIdx.x >> 6, lane = threadIdx.x & 63;
  const int tbase = blockIdx.x * PPB;
  const int pt0 = wv * 4;
  const int n = 2 * lane;

#pragma unroll
  for (int j = 0; j < 4; ++j) {
    const int t = tbase + pt0 + j;
    const int b = t >> 16;
    const int v = idxbuf[t];
    ushort2 nv = *(const ushort2*)((const unsigned short*)net + (size_t)t * 128 + n);
    sx[pt0 + j][n]     = us2f(nv.x);
    sx[pt0 + j][n + 1] = us2f(nv.y);
    const unsigned* frow = fea + (((size_t)((b << 15) | v)) << 7);
    uint2 fv = *(const uint2*)(frow + n);
    sx[pt0 + j][128 + n]     = dec_max(fv.x);
    sx[pt0 + j][128 + n + 1] = dec_max(fv.y);
  }

  resblock16(swb, sx, sh, w0, b0, w1, b1, wsc, wv, lane, tbase, net);
}

// fc_c + scatter-sum + count
__global__ __launch_bounds__(256) void k_fc_c(
    const unsigned short* __restrict__ net, const int* __restrict__ idxbuf,
    const float* __restrict__ wc, const float* __restrict__ bc,
    float* __restrict__ sums, float* __restrict__ cnt)
{
  __shared__ float swb[8192];
  __shared__ float sxx[PPB][128];
  const int wv = threadIdx.x >> 6, lane = threadIdx.x & 63;
  const int tbase = blockIdx.x * PPB;
  const int pt0 = wv * 4;
  const int n = 2 * lane;

#pragma unroll
  for (int j = 0; j < 4; ++j) {
    const int t = tbase + pt0 + j;
    ushort2 nv = *(const ushort2*)(net + (size_t)t * 128 + n);
    sxx[pt0 + j][n]     = us2f(nv.x);
    sxx[pt0 + j][n + 1] = us2f(nv.y);
  }

  float2 a[4];
  {
    float2 bb = *(const float2*)(bc + n);
#pragma unroll
    for (int j = 0; j < 4; ++j) a[j] = bb;
  }
  for (int k0 = 0; k0 < 128; k0 += 64) {
    __syncthreads();
    const float4* src = (const float4*)(wc + (size_t)k0 * 128);
    float4* dst = (float4*)swb;
    for (int i = threadIdx.x; i < 2048; i += 256) dst[i] = src[i];
    __syncthreads();
#pragma unroll 4
    for (int kk = 0; kk < 64; ++kk) {
      float2 wv2 = *(const float2*)(swb + kk * 128 + n);
#pragma unroll
      for (int j = 0; j < 4; ++j) {
        float xv = sxx[pt0 + j][k0 + kk];
        a[j].x += xv * wv2.x;
        a[j].y += xv * wv2.y;
      }
    }
  }

#pragma unroll
  for (int j = 0; j < 4; ++j) {
    const int t = tbase + pt0 + j;
    const int b = t >> 16;
    const int v = idxbuf[t];
    float* srow = sums + (((size_t)((b << 15) | v)) << 7);
    atomicAdd(&srow[n],     a[j].x);
    atomicAdd(&srow[n + 1], a[j].y);
    if (lane == 0) atomicAdd(&cnt[(b << 15) | v], 1.0f);
  }
}

// mean + transpose: out[b, c, v] = sums[b, v, c] / max(cnt, 1)
__global__ __launch_bounds__(256) void k_write(
    const float* __restrict__ sums, const float* __restrict__ cnt,
    float* __restrict__ out)
{
  const int gid = blockIdx.x * 256 + threadIdx.x;
  const int v = gid & 32767;
  const int c = (gid >> 15) & 127;
  const int b = gid >> 22;
  float cn = cnt[(b << 15) | v];
  float m = sums[(((size_t)((b << 15) | v)) << 7) + c] / fmaxf(cn, 1.0f);
  out[gid] = m;
}

extern "C" void kernel_launch(void* const* d_in, const int* in_sizes, int n_in,
                              void* d_out, int out_size, void* d_ws, size_t ws_size,
                              hipStream_t stream)
{
  const float* p    = (const float*)d_in[0];
  const float* wpos = (const float*)d_in[1];
  const float* bpos = (const float*)d_in[2];
  const float* w0   = (const float*)d_in[3];
  const float* b0   = (const float*)d_in[4];
  const float* w1   = (const float*)d_in[5];
  const float* b1   = (const float*)d_in[6];
  const float* wsc  = (const float*)d_in[7];
  const float* wc   = (const float*)d_in[8];
  const float* bc   = (const float*)d_in[9];

  char* ws = (char*)d_ws;
  int* idxbuf   = (int*)ws;                                    // 1 MiB
  bf16* net     = (bf16*)(ws + (1u << 20));                    // 64 MiB
  unsigned* fea = (unsigned*)(ws + (1u << 20) + (64u << 20));  // 64 MiB (reused as f32 sums)
  float* cnt    = (float*)(ws + (1u << 20) + (128u << 20));    // 512 KiB

  const size_t fea_bytes = (size_t)BATCH * R3 * 128 * 4;

  k_first<<<NPTS / PPB, 256, 0, stream>>>(p, wpos, bpos, w0, b0, w1, b1, wsc, net, idxbuf);

  for (int i = 1; i < 5; ++i) {
    hipMemsetAsync(fea, 0, fea_bytes, stream);
    k_pool<<<(NPTS * 128) / 256, 256, 0, stream>>>((const unsigned short*)net, idxbuf, fea);
    k_res<<<NPTS / PPB, 256, 0, stream>>>(net, fea, idxbuf,
        w0 + (size_t)i * 256 * 128, b0 + (size_t)i * 128,
        w1 + (size_t)i * 128 * 128, b1 + (size_t)i * 128,
        wsc + (size_t)i * 256 * 128);
  }

  hipMemsetAsync(fea, 0, fea_bytes, stream);
  hipMemsetAsync(cnt, 0, (size_t)BATCH * R3 * 4, stream);
  k_fc_c<<<NPTS / PPB, 256, 0, stream>>>((const unsigned short*)net, idxbuf, wc, bc,
                                         (float*)fea, cnt);
  k_write<<<out_size / 256, 256, 0, stream>>>((const float*)fea, cnt, (float*)d_out);
}